// Round 11
// baseline (371.575 us; speedup 1.0000x reference)
//
#include <hip/hip_runtime.h>

// ---------------------------------------------------------------------------
// Fused NeRF MLP forward: 262144 rows, 63-in, 8x256 hidden + skip at L4->L5,
// 4-dim output. fp16 MFMA (16x16x32, swapped operands) with fp32 accum.
//
// R11 = R8 scheme scaled to M=128 samples/block:
//   wave = 128 samples x 64 ncols, acc[4][8] = 128 VGPR, pf depth-2.
//   LDS = hbuf 64KB + xbuf 16KB = 81920 B unpadded+XOR-swizzled (R4-proven
//   addressing) -> EXACTLY 2 blocks/CU (163840 B). 8 waves/CU.
//   Why: R10 proved per-wave MFMA duty scales with MFMA-per-barrier-segment
//   (3.65->5.0 %/wave when segments doubled); M=128 doubles segment size
//   (256 MFMA/wave) at unchanged occupancy vs R10, and HALVES per-sample W
//   traffic (2048 blocks x ~1MB) - the R6 failure mode in reverse.
// __launch_bounds__(256,2): 256-reg budget, no R4-style spill.
// ---------------------------------------------------------------------------

typedef _Float16 h8 __attribute__((ext_vector_type(8)));
typedef float f4 __attribute__((ext_vector_type(4)));

// fragment-linear weight offsets, in halves (16x16x32 format, same as R8):
#define OFF_L0   0
#define OFF_L1   16384
#define OFF_L2   81920
#define OFF_L3   147456
#define OFF_L4   212992
#define OFF_L5   278528
#define OFF_L6   360448
#define OFF_L7   425984
#define OFF_OUT  491520
#define TOT_HALVES 495616
#define TOT_GROUPS (TOT_HALVES / 8)   // 61952

__global__ void nerf_prep(const float* __restrict__ W0, const float* __restrict__ W1,
                          const float* __restrict__ W2, const float* __restrict__ W3,
                          const float* __restrict__ W4, const float* __restrict__ W5,
                          const float* __restrict__ W6, const float* __restrict__ W7,
                          const float* __restrict__ Wout, _Float16* __restrict__ wf)
{
    int g = blockIdx.x * 256 + threadIdx.x;     // one 8-half fragment group
    if (g >= TOT_GROUPS) return;

    const int bounds[10] = {0, 2048, 10240, 18432, 26624, 34816, 45056, 53248, 61440, 61952};
    const float* Ws[9] = {W0, W1, W2, W3, W4, W5, W6, W7, Wout};

    int L = 0;
    while (L < 8 && g >= bounds[L + 1]) ++L;

    int t    = g - bounds[L];
    int lane = t & 63;
    int q    = t >> 6;
    int NF   = (L == 8) ? 1 : 16;
    int nf   = q % NF;
    int ks   = q / NF;
    int n    = nf * 16 + (lane & 15);
    int k0   = ks * 32 + (lane >> 4) * 8;

    const float* W = Ws[L];
    h8 v;
#pragma unroll
    for (int i = 0; i < 8; ++i) {
        int k = k0 + i;
        float val = 0.f;
        if (L == 0) {
            if (k < 63) val = W[k * 256 + n];                 // 63x256, pad k=63
        } else if (L == 5) {
            // k' < 256 -> h part (orig row 63+k'); k' >= 256 -> x part (orig row k'-256)
            if (k < 256)             val = W[(63 + k) * 256 + n];
            else if ((k - 256) < 63) val = W[(k - 256) * 256 + n];
        } else if (L == 8) {
            if (n < 4) val = W[k * 4 + n];                    // 256x4, pad n to 16
        } else {
            val = W[k * 256 + n];                             // 256x256
        }
        v[i] = (_Float16)val;
    }
    *(h8*)(wf + (size_t)g * 8) = v;
}

__device__ __forceinline__ const h8* bfrag_ptr(const _Float16* __restrict__ w,
                                               int ks, int wid, int nf, int lane)
{
    return (const h8*)(w + (size_t)((ks * 16 + (wid * 4 + nf)) * 64 + lane) * 8);
}

// XOR-swizzled LDS addressing (R4-proven): byte ^= (row&7)<<4.
// Bijective within each row-octet; preserves 16B blocks (b128 align OK,
// b64 writes at 8B offsets stay inside their relocated 16B block).
__device__ __forceinline__ char* hgen(_Float16* h, int row, int col)
{
    int byte = (row << 9) + (col << 1);      // row stride 512B (256 halves)
    byte ^= (row & 7) << 4;
    return (char*)h + byte;
}
__device__ __forceinline__ char* xgen(_Float16* xb, int row, int col)
{
    int byte = (row << 7) + (col << 1);      // row stride 128B (64 halves)
    byte ^= (row & 7) << 4;
    return (char*)xb + byte;
}

// Barrier without vmcnt drain (keeps cross-layer W-prefetch loads in flight).
__device__ __forceinline__ void barrier_nodrain()
{
    asm volatile("s_waitcnt lgkmcnt(0)" ::: "memory");
    __builtin_amdgcn_s_barrier();
    __builtin_amdgcn_sched_barrier(0);
}

// MODE: 0 = h from hbuf, 1 = h from xbuf (L0), 2 = hbuf then xbuf (L5 skip)
// Wave = all 128 samples (sf 0..7) x 64 ncols (slots 4wid..4wid+3).
// pf: depth-2 prefetch; on entry pf[0]/pf[1] hold this layer's ks=0/1
// W-frags; on exit (!LAST) they hold the NEXT layer's ks=0/1.
template <int KSTEPS, int MODE, bool LAST>
__device__ __forceinline__ void mlp_layer(_Float16* hbuf, _Float16* xbuf,
                                          const _Float16* __restrict__ wfrag,
                                          const _Float16* __restrict__ wnext,
                                          const float* __restrict__ bias,
                                          int wid, int lane, h8 (&pf)[2][4])
{
    const int lg = lane >> 4, ln = lane & 15;

    // bias as float4 per cf: ncols wid*64 + cf*16 + lg*4 + (0..3)
    f4 bv[4];
#pragma unroll
    for (int cf = 0; cf < 4; ++cf)
        bv[cf] = *(const f4*)&bias[wid * 64 + cf * 16 + lg * 4];

    // accumulator INITIALIZED with bias
    f4 acc[4][8];   // [cf][sf]
#pragma unroll
    for (int cf = 0; cf < 4; ++cf)
#pragma unroll
        for (int sf = 0; sf < 8; ++sf)
            acc[cf][sf] = bv[cf];

#pragma unroll
    for (int ks = 0; ks < KSTEPS; ++ks) {
        __builtin_amdgcn_s_setprio(1);
#pragma unroll
        for (int sf = 0; sf < 8; ++sf) {
            const char* ap;
            if constexpr (MODE == 1) {
                ap = xgen(xbuf, sf * 16 + ln, ks * 32 + lg * 8);
            } else if constexpr (MODE == 2) {
                ap = (ks < 8) ? hgen(hbuf, sf * 16 + ln, ks * 32 + lg * 8)
                              : xgen(xbuf, sf * 16 + ln, (ks - 8) * 32 + lg * 8);
            } else {
                ap = hgen(hbuf, sf * 16 + ln, ks * 32 + lg * 8);
            }
            h8 hfr = *(const h8*)ap;
#pragma unroll
            for (int cf = 0; cf < 4; ++cf)
                acc[cf][sf] = __builtin_amdgcn_mfma_f32_16x16x32_f16(pf[ks & 1][cf], hfr, acc[cf][sf], 0, 0, 0);
        }
        __builtin_amdgcn_s_setprio(0);
        // refill the buffer just consumed: ks+2 of this layer, or ks=0/1 of next
        if (ks + 2 < KSTEPS) {
#pragma unroll
            for (int cf = 0; cf < 4; ++cf)
                pf[ks & 1][cf] = *bfrag_ptr(wfrag, ks + 2, wid, cf, lane);
        } else {
            if constexpr (!LAST) {
#pragma unroll
                for (int cf = 0; cf < 4; ++cf)
                    pf[ks & 1][cf] = *bfrag_ptr(wnext, ks + 2 - KSTEPS, wid, cf, lane);
            }
        }
    }

    barrier_nodrain();   // WAR: all reads of hbuf done before overwrite

    // packed epilogue: relu+cvt, 4 ncols -> one b64 per (cf,sf)
    // D layout (m89): col=ln=sample-in-16, row=lg*4+reg=ncol-in-16
#pragma unroll
    for (int cf = 0; cf < 4; ++cf) {
#pragma unroll
        for (int sf = 0; sf < 8; ++sf) {
            union { _Float16 h[4]; unsigned long long u; } p;
#pragma unroll
            for (int i = 0; i < 4; ++i)
                p.h[i] = (_Float16)fmaxf(acc[cf][sf][i], 0.f);
            *(unsigned long long*)hgen(hbuf, sf * 16 + ln, wid * 64 + cf * 16 + lg * 4) = p.u;
        }
    }
    barrier_nodrain();   // RAW: writes visible before next layer reads
}

__global__ __launch_bounds__(256, 2) void nerf_fused(
    const float* __restrict__ x,
    const float* __restrict__ b0, const float* __restrict__ b1, const float* __restrict__ b2,
    const float* __restrict__ b3, const float* __restrict__ b4, const float* __restrict__ b5,
    const float* __restrict__ b6, const float* __restrict__ b7, const float* __restrict__ bout,
    const _Float16* __restrict__ wf,
    float* __restrict__ out)
{
    __shared__ _Float16 hbuf[128 * 256];  // 65536 B, XOR-swizzled
    __shared__ _Float16 xbuf[128 * 64];   // 16384 B, XOR-swizzled; total 81920 B

    const int tid  = threadIdx.x;
    const int wid  = tid >> 6;
    const int lane = tid & 63;
    const int lg   = lane >> 4, ln = lane & 15;
    const int row0 = blockIdx.x * 128;

    // prologue: L0's ks=0,1 W-frag loads in flight during x-staging
    h8 pf[2][4];
#pragma unroll
    for (int s = 0; s < 2; ++s)
#pragma unroll
        for (int cf = 0; cf < 4; ++cf)
            pf[s][cf] = *bfrag_ptr(wf + OFF_L0, s, wid, cf, lane);

    // stage x[:, 0:63] -> fp16, zero-pad col 63 (128 rows)
    for (int idx = tid; idx < 128 * 64; idx += 256) {
        int r = idx >> 6, c = idx & 63;
        float v = (c < 63) ? x[(size_t)(row0 + r) * 90 + c] : 0.f;
        *(_Float16*)xgen(xbuf, r, c) = (_Float16)v;
    }
    barrier_nodrain();

    mlp_layer<2,  1, false>(hbuf, xbuf, wf + OFF_L0, wf + OFF_L1, b0, wid, lane, pf);
    mlp_layer<8,  0, false>(hbuf, xbuf, wf + OFF_L1, wf + OFF_L2, b1, wid, lane, pf);
    mlp_layer<8,  0, false>(hbuf, xbuf, wf + OFF_L2, wf + OFF_L3, b2, wid, lane, pf);
    mlp_layer<8,  0, false>(hbuf, xbuf, wf + OFF_L3, wf + OFF_L4, b3, wid, lane, pf);
    mlp_layer<8,  0, false>(hbuf, xbuf, wf + OFF_L4, wf + OFF_L5, b4, wid, lane, pf);
    mlp_layer<10, 2, false>(hbuf, xbuf, wf + OFF_L5, wf + OFF_L6, b5, wid, lane, pf);
    mlp_layer<8,  0, false>(hbuf, xbuf, wf + OFF_L6, wf + OFF_L7, b6, wid, lane, pf);
    mlp_layer<8,  0, true >(hbuf, xbuf, wf + OFF_L7, wf + OFF_L7, b7, wid, lane, pf);

    // output layer 256 -> 4 (padded to 16 cols), UNswapped path:
    // wave wid owns rows [wid*32, wid*32+32): two 16-row passes
#pragma unroll
    for (int half = 0; half < 2; ++half) {
        f4 oacc;
#pragma unroll
        for (int i = 0; i < 4; ++i) oacc[i] = 0.f;
#pragma unroll
        for (int ks = 0; ks < 8; ++ks) {
            h8 bfr = *(const h8*)(wf + OFF_OUT + (size_t)(ks * 64 + lane) * 8);
            h8 afr = *(const h8*)hgen(hbuf, wid * 32 + half * 16 + ln, ks * 32 + lg * 8);
            oacc = __builtin_amdgcn_mfma_f32_16x16x32_f16(afr, bfr, oacc, 0, 0, 0);
        }
        if (ln < 4) {
            float bo = bout[ln];
#pragma unroll
            for (int i = 0; i < 4; ++i) {
                int r = row0 + wid * 32 + half * 16 + lg * 4 + i;
                out[(size_t)r * 4 + ln] = oacc[i] + bo;
            }
        }
    }
}

extern "C" void kernel_launch(void* const* d_in, const int* in_sizes, int n_in,
                              void* d_out, int out_size, void* d_ws, size_t ws_size,
                              hipStream_t stream)
{
    const float* x = (const float*)d_in[0];
    const float* W[9];
    const float* b[9];
    for (int i = 0; i < 8; ++i) {
        W[i] = (const float*)d_in[1 + 2 * i];
        b[i] = (const float*)d_in[2 + 2 * i];
    }
    W[8] = (const float*)d_in[17];   // Wout
    b[8] = (const float*)d_in[18];   // bout

    _Float16* wf = (_Float16*)d_ws;

    nerf_prep<<<(TOT_GROUPS + 255) / 256, 256, 0, stream>>>(
        W[0], W[1], W[2], W[3], W[4], W[5], W[6], W[7], W[8], wf);

    nerf_fused<<<262144 / 128, 256, 0, stream>>>(
        x, b[0], b[1], b[2], b[3], b[4], b[5], b[6], b[7], b[8], wf,
        (float*)d_out);
}

// Round 12
// 254.838 us; speedup vs baseline: 1.4581x; 1.4581x over previous
//
#include <hip/hip_runtime.h>

// ---------------------------------------------------------------------------
// Fused NeRF MLP forward: 262144 rows, 63-in, 8x256 hidden + skip at L4->L5,
// 4-dim output. fp16 MFMA (16x16x32, swapped operands) with fp32 accum.
//
// R12 = R8 base (proven best: 277us profiled) + two convoy-breakers:
//  1. One-time inter-block phase stagger: first-round blocks (id<768) delay
//     ((bid>>3)%3)*~5k cyc. A CU's 3 resident blocks otherwise start/finish
//     in lockstep forever (same code length), so their MFMA-free epilogue
//     windows coincide and the matrix pipe idles CU-wide (~44% util across
//     ALL structures R2..R11). Staggered slots stay staggered (slots free at
//     staggered times).
//  2. cvt-hoist: relu+cvt+pack computed into registers BEFORE the WAR
//     barrier (sched_barrier(0) was pinning them after); only 16 ds_write_b64
//     remain in the barrier-locked MFMA-free window.
// R11 lesson: with AGPR accumulators the arch-VGPR side caps near half the
// unified budget -> acc must stay <=64; no more big-acc experiments.
// ---------------------------------------------------------------------------

typedef _Float16 h8 __attribute__((ext_vector_type(8)));
typedef float f4 __attribute__((ext_vector_type(4)));

// fragment-linear weight offsets, in halves:
#define OFF_L0   0
#define OFF_L1   16384
#define OFF_L2   81920
#define OFF_L3   147456
#define OFF_L4   212992
#define OFF_L5   278528
#define OFF_L6   360448
#define OFF_L7   425984
#define OFF_OUT  491520
#define TOT_HALVES 495616
#define TOT_GROUPS (TOT_HALVES / 8)   // 61952

__global__ void nerf_prep(const float* __restrict__ W0, const float* __restrict__ W1,
                          const float* __restrict__ W2, const float* __restrict__ W3,
                          const float* __restrict__ W4, const float* __restrict__ W5,
                          const float* __restrict__ W6, const float* __restrict__ W7,
                          const float* __restrict__ Wout, _Float16* __restrict__ wf)
{
    int g = blockIdx.x * 256 + threadIdx.x;     // one 8-half fragment group
    if (g >= TOT_GROUPS) return;

    const int bounds[10] = {0, 2048, 10240, 18432, 26624, 34816, 45056, 53248, 61440, 61952};
    const float* Ws[9] = {W0, W1, W2, W3, W4, W5, W6, W7, Wout};

    int L = 0;
    while (L < 8 && g >= bounds[L + 1]) ++L;

    int t    = g - bounds[L];
    int lane = t & 63;
    int q    = t >> 6;
    int NF   = (L == 8) ? 1 : 16;
    int nf   = q % NF;
    int ks   = q / NF;
    int n    = nf * 16 + (lane & 15);
    int k0   = ks * 32 + (lane >> 4) * 8;

    const float* W = Ws[L];
    h8 v;
#pragma unroll
    for (int i = 0; i < 8; ++i) {
        int k = k0 + i;
        float val = 0.f;
        if (L == 0) {
            if (k < 63) val = W[k * 256 + n];                 // 63x256, pad k=63
        } else if (L == 5) {
            // k' < 256 -> h part (orig row 63+k'); k' >= 256 -> x part (orig row k'-256)
            if (k < 256)             val = W[(63 + k) * 256 + n];
            else if ((k - 256) < 63) val = W[(k - 256) * 256 + n];
        } else if (L == 8) {
            if (n < 4) val = W[k * 4 + n];                    // 256x4, pad n to 16
        } else {
            val = W[k * 256 + n];                             // 256x256
        }
        v[i] = (_Float16)val;
    }
    *(h8*)(wf + (size_t)g * 8) = v;
}

__device__ __forceinline__ const h8* bfrag_ptr(const _Float16* __restrict__ w,
                                               int ks, int wid, int nf, int lane)
{
    return (const h8*)(w + (size_t)((ks * 16 + (wid * 4 + nf)) * 64 + lane) * 8);
}

// Barrier without vmcnt drain (keeps cross-layer W-prefetch loads in flight).
__device__ __forceinline__ void barrier_nodrain()
{
    asm volatile("s_waitcnt lgkmcnt(0)" ::: "memory");
    __builtin_amdgcn_s_barrier();
    __builtin_amdgcn_sched_barrier(0);
}

// MODE: 0 = h from hbuf, 1 = h from xbuf (layer 0), 2 = hbuf then xbuf (layer 5)
// pf: depth-3 rolling W prefetch (slot = global kstep % 3, GB3 = gbase % 3).
template <int KSTEPS, int MODE, int GB3, bool LAST>
__device__ __forceinline__ void mlp_layer(_Float16 (&hbuf)[64][264], _Float16 (&xbuf)[64][72],
                                          const _Float16* __restrict__ wfrag,
                                          const _Float16* __restrict__ wnext,
                                          const float* __restrict__ bias,
                                          int wid, int lane, h8 (&pf)[3][4])
{
    const int lg = lane >> 4, ln = lane & 15;

    // bias as float4 per cf: ncols wid*64 + cf*16 + lg*4 + (0..3)
    f4 bv[4];
#pragma unroll
    for (int cf = 0; cf < 4; ++cf)
        bv[cf] = *(const f4*)&bias[wid * 64 + cf * 16 + lg * 4];

    // accumulator INITIALIZED with bias
    f4 acc[4][4];   // [cf][sf]
#pragma unroll
    for (int cf = 0; cf < 4; ++cf)
#pragma unroll
        for (int sf = 0; sf < 4; ++sf)
            acc[cf][sf] = bv[cf];

#pragma unroll
    for (int ks = 0; ks < KSTEPS; ++ks) {
        const int slot = (GB3 + ks) % 3;      // folds to constant after unroll
        __builtin_amdgcn_s_setprio(1);
        h8 hfr[4];
#pragma unroll
        for (int sf = 0; sf < 4; ++sf) {
            const _Float16* ap;
            if constexpr (MODE == 1) {
                ap = &xbuf[sf * 16 + ln][ks * 32 + lg * 8];
            } else if constexpr (MODE == 2) {
                ap = (ks < 8) ? &hbuf[sf * 16 + ln][ks * 32 + lg * 8]
                              : &xbuf[sf * 16 + ln][(ks - 8) * 32 + lg * 8];
            } else {
                ap = &hbuf[sf * 16 + ln][ks * 32 + lg * 8];
            }
            hfr[sf] = *(const h8*)ap;
        }
#pragma unroll
        for (int cf = 0; cf < 4; ++cf)
#pragma unroll
            for (int sf = 0; sf < 4; ++sf)
                acc[cf][sf] = __builtin_amdgcn_mfma_f32_16x16x32_f16(pf[slot][cf], hfr[sf], acc[cf][sf], 0, 0, 0);
        __builtin_amdgcn_s_setprio(0);
        // refill the slot just consumed with global kstep g+3
        if (ks + 3 < KSTEPS) {
#pragma unroll
            for (int cf = 0; cf < 4; ++cf)
                pf[slot][cf] = *bfrag_ptr(wfrag, ks + 3, wid, cf, lane);
        } else {
            if constexpr (!LAST) {
#pragma unroll
                for (int cf = 0; cf < 4; ++cf)
                    pf[slot][cf] = *bfrag_ptr(wnext, ks + 3 - KSTEPS, wid, cf, lane);
            }
        }
    }

    // cvt-HOIST: relu + cvt + pack BEFORE the barrier (overlappable with other
    // blocks' MFMA phases); only the 16 ds_write_b64 sit after it.
    unsigned long long pu[4][4];
#pragma unroll
    for (int cf = 0; cf < 4; ++cf) {
#pragma unroll
        for (int sf = 0; sf < 4; ++sf) {
            union { _Float16 h[4]; unsigned long long u; } p;
#pragma unroll
            for (int i = 0; i < 4; ++i)
                p.h[i] = (_Float16)fmaxf(acc[cf][sf][i], 0.f);
            pu[cf][sf] = p.u;
        }
    }

    barrier_nodrain();   // WAR: everyone done reading hbuf

    // D layout (m89): col=ln=sample-within-16, row=lg*4+reg=ncol-within-16
#pragma unroll
    for (int cf = 0; cf < 4; ++cf)
#pragma unroll
        for (int sf = 0; sf < 4; ++sf)
            *(unsigned long long*)&hbuf[sf * 16 + ln][wid * 64 + cf * 16 + lg * 4] = pu[cf][sf];

    barrier_nodrain();   // RAW: writes visible before next layer's reads
}

__global__ __launch_bounds__(256, 3) void nerf_fused(
    const float* __restrict__ x,
    const float* __restrict__ b0, const float* __restrict__ b1, const float* __restrict__ b2,
    const float* __restrict__ b3, const float* __restrict__ b4, const float* __restrict__ b5,
    const float* __restrict__ b6, const float* __restrict__ b7, const float* __restrict__ bout,
    const _Float16* __restrict__ wf,
    float* __restrict__ out)
{
    __shared__ _Float16 hbuf[64][264];   // proven padded layout
    __shared__ _Float16 xbuf[64][72];

    const int tid  = threadIdx.x;
    const int wid  = tid >> 6;
    const int lane = tid & 63;
    const int lg   = lane >> 4, ln = lane & 15;
    const int row0 = blockIdx.x * 64;

    // ---- phase stagger (first resident round only): break inter-block
    // lockstep so the 3 blocks/CU anti-phase their epilogue windows.
    // (bid>>3)%3 gives distinct phases to same-CU trios under either
    // CU-major or XCD-round-robin fill order. ~5k cyc per phase step.
    if (blockIdx.x < 768) {
        int ph = (blockIdx.x >> 3) % 3;
        for (int i = 0; i < ph * 10; ++i)
            asm volatile("s_sleep 8");
    }

    // prologue: globals 0,1,2 = L0 ks0, L0 ks1, L1 ks0 into slots 0,1,2
    h8 pf[3][4];
#pragma unroll
    for (int cf = 0; cf < 4; ++cf) {
        pf[0][cf] = *bfrag_ptr(wf + OFF_L0, 0, wid, cf, lane);
        pf[1][cf] = *bfrag_ptr(wf + OFF_L0, 1, wid, cf, lane);
        pf[2][cf] = *bfrag_ptr(wf + OFF_L1, 0, wid, cf, lane);
    }

    // stage x[:, 0:63] -> fp16, zero-pad col 63
    for (int idx = tid; idx < 64 * 64; idx += 256) {
        int r = idx >> 6, c = idx & 63;
        float v = (c < 63) ? x[(size_t)(row0 + r) * 90 + c] : 0.f;
        xbuf[r][c] = (_Float16)v;
    }
    barrier_nodrain();

    // gbase per layer: 0,2,10,18,26,34,44,52 -> %3 = 0,2,1,0,2,1,2,1
    mlp_layer<2,  1, 0, false>(hbuf, xbuf, wf + OFF_L0, wf + OFF_L1, b0, wid, lane, pf);
    mlp_layer<8,  0, 2, false>(hbuf, xbuf, wf + OFF_L1, wf + OFF_L2, b1, wid, lane, pf);
    mlp_layer<8,  0, 1, false>(hbuf, xbuf, wf + OFF_L2, wf + OFF_L3, b2, wid, lane, pf);
    mlp_layer<8,  0, 0, false>(hbuf, xbuf, wf + OFF_L3, wf + OFF_L4, b3, wid, lane, pf);
    mlp_layer<8,  0, 2, false>(hbuf, xbuf, wf + OFF_L4, wf + OFF_L5, b4, wid, lane, pf);
    mlp_layer<10, 2, 1, false>(hbuf, xbuf, wf + OFF_L5, wf + OFF_L6, b5, wid, lane, pf);
    mlp_layer<8,  0, 2, false>(hbuf, xbuf, wf + OFF_L6, wf + OFF_L7, b6, wid, lane, pf);
    mlp_layer<8,  0, 1, true >(hbuf, xbuf, wf + OFF_L7, wf + OFF_L7, b7, wid, lane, pf);

    // output layer 256 -> 4 (padded to 16 cols), UNswapped path:
    // wave wid owns rows [16*wid, 16*wid+16)
    f4 oacc;
#pragma unroll
    for (int i = 0; i < 4; ++i) oacc[i] = 0.f;
#pragma unroll
    for (int ks = 0; ks < 8; ++ks) {
        h8 bfr = *(const h8*)(wf + OFF_OUT + (size_t)(ks * 64 + lane) * 8);
        h8 afr = *(const h8*)&hbuf[wid * 16 + ln][ks * 32 + lg * 8];
        oacc = __builtin_amdgcn_mfma_f32_16x16x32_f16(afr, bfr, oacc, 0, 0, 0);
    }
    if (ln < 4) {
        float bo = bout[ln];
#pragma unroll
        for (int i = 0; i < 4; ++i) {
            int r = row0 + wid * 16 + lg * 4 + i;
            out[(size_t)r * 4 + ln] = oacc[i] + bo;
        }
    }
}

extern "C" void kernel_launch(void* const* d_in, const int* in_sizes, int n_in,
                              void* d_out, int out_size, void* d_ws, size_t ws_size,
                              hipStream_t stream)
{
    const float* x = (const float*)d_in[0];
    const float* W[9];
    const float* b[9];
    for (int i = 0; i < 8; ++i) {
        W[i] = (const float*)d_in[1 + 2 * i];
        b[i] = (const float*)d_in[2 + 2 * i];
    }
    W[8] = (const float*)d_in[17];   // Wout
    b[8] = (const float*)d_in[18];   // bout

    _Float16* wf = (_Float16*)d_ws;

    nerf_prep<<<(TOT_GROUPS + 255) / 256, 256, 0, stream>>>(
        W[0], W[1], W[2], W[3], W[4], W[5], W[6], W[7], W[8], wf);

    nerf_fused<<<262144 / 64, 256, 0, stream>>>(
        x, b[0], b[1], b[2], b[3], b[4], b[5], b[6], b[7], b[8], wf,
        (float*)d_out);
}